// Round 14
// baseline (554.850 us; speedup 1.0000x reference)
//
#include <hip/hip_runtime.h>
#include <hip/hip_bf16.h>

#define EMBED 256
#define LL 6
#define GRID 512          // 2 blocks/CU x 256 CUs -> guaranteed co-resident
#define PREPB 33          // block 0 = prep, 1..32 = Wt tiles
#define CHUNK4 4096       // float4 per copy chunk (64 KB)

typedef __attribute__((ext_vector_type(8))) __bf16 bf16x8;
typedef __attribute__((ext_vector_type(4))) float f32x4;

// sigmoid(x) > 0.05  <=>  x > -ln(19)
#define SEL_THR (-2.9444389791664403f)

struct PlanAll {
    const float *clsL, *rt, *W0, *W1, *b0, *b1;
    const float *vsrc[5];            // q, qp, cls, coord, ref
    const float *icls, *icoord, *iref;
    const float *q0, *q1;
    float* calib; int* bbox; int* cnt; int* bar;
    __bf16 *Wt0, *Wt1; float *bvec0, *bvec1;
    int n4[5]; int vdst[5]; int perLay4[5]; int layStride[5];
    int cstart[6];
    int n;                            // select element count
    int nT, gblk, gemmOff0, gemmOff1, dcls, dcoord, dref;
    int K, NI, NV, N;
};

__device__ __forceinline__ float inv_sig(float v) {
    v = fminf(fmaxf(v, 0.0f), 1.0f);
    float x1 = fmaxf(v, 1e-5f);
    float x2 = fmaxf(1.0f - v, 1e-5f);
    return logf(x1 / x2);
}

__device__ __forceinline__ bf16x8 cvt8(float4 f0, float4 f1) {
    bf16x8 r;
    r[0] = (__bf16)f0.x; r[1] = (__bf16)f0.y; r[2] = (__bf16)f0.z; r[3] = (__bf16)f0.w;
    r[4] = (__bf16)f1.x; r[5] = (__bf16)f1.y; r[6] = (__bf16)f1.z; r[7] = (__bf16)f1.w;
    return r;
}

// 64 rows x 256 cols per tile (R3/R6/R12-proven)
__device__ void gemm_block(const float* __restrict__ q, const __bf16* __restrict__ Wt,
                           const float* __restrict__ bvec, const int* __restrict__ bbox,
                           float* __restrict__ out, int NI, int K, int out_off, int lb) {
    int tid  = threadIdx.x;
    int w    = tid >> 6;
    int lane = tid & 63;
    int lo16 = lane & 15;
    int kg   = lane >> 4;
    int r0 = lb * 64;

    const float* aptr[4];
#pragma unroll
    for (int t = 0; t < 4; ++t) {
        int row = r0 + 16 * t + lo16;
        int rc = min(row, K - 1);
        int box = bbox[rc]; box = max(0, min(box, NI - 1));
        aptr[t] = q + (size_t)box * EMBED + kg * 8;
    }
    const __bf16* bptr[4];
#pragma unroll
    for (int t = 0; t < 4; ++t) {
        int col = w * 64 + 16 * t + lo16;
        bptr[t] = Wt + (size_t)col * EMBED + kg * 8;
    }

    f32x4 acc[4][4];
#pragma unroll
    for (int ct = 0; ct < 4; ++ct) {
        float bv = bvec[w * 64 + 16 * ct + lo16];
#pragma unroll
        for (int rt = 0; rt < 4; ++rt) {
            acc[rt][ct][0] = bv; acc[rt][ct][1] = bv; acc[rt][ct][2] = bv; acc[rt][ct][3] = bv;
        }
    }
    for (int s = 0; s < 8; ++s) {
        bf16x8 a[4], b[4];
#pragma unroll
        for (int t = 0; t < 4; ++t) {
            float4 f0 = *(const float4*)(aptr[t] + s * 32);
            float4 f1 = *(const float4*)(aptr[t] + s * 32 + 4);
            a[t] = cvt8(f0, f1);
            b[t] = *(const bf16x8*)(bptr[t] + s * 32);
        }
#pragma unroll
        for (int rt = 0; rt < 4; ++rt)
#pragma unroll
            for (int ct = 0; ct < 4; ++ct)
                acc[rt][ct] = __builtin_amdgcn_mfma_f32_16x16x32_bf16(a[rt], b[ct], acc[rt][ct], 0, 0, 0);
    }
#pragma unroll
    for (int rt = 0; rt < 4; ++rt) {
#pragma unroll
        for (int reg = 0; reg < 4; ++reg) {
            int row = r0 + 16 * rt + kg * 4 + reg;
            if (row < K) {
#pragma unroll
                for (int ct = 0; ct < 4; ++ct) {
                    int col = w * 64 + 16 * ct + lo16;
                    out[out_off + (size_t)row * EMBED + col] = acc[rt][ct][reg];
                }
            }
        }
    }
}

__global__ __launch_bounds__(256, 2) void k_all(PlanAll P, float* __restrict__ out) {
    __shared__ float T[64][65];
    __shared__ int warpCnt[4];
    __shared__ float s_calib[16];
    int bid = blockIdx.x, tid = threadIdx.x;

    // ======================= PHASE 1 =======================
    if (bid == 0) {
        // ---- calib (thread 0) ----
        if (tid == 0) {
            double a[4][8];
            for (int i = 0; i < 4; ++i)
                for (int j = 0; j < 4; ++j) {
                    a[i][j]     = (double)P.rt[j * 4 + i];
                    a[i][4 + j] = (i == j) ? 1.0 : 0.0;
                }
            for (int c = 0; c < 4; ++c) {
                int p = c; double best = fabs(a[c][c]);
                for (int r = c + 1; r < 4; ++r) { double v = fabs(a[r][c]); if (v > best) { best = v; p = r; } }
                if (p != c) for (int j = 0; j < 8; ++j) { double t2 = a[c][j]; a[c][j] = a[p][j]; a[p][j] = t2; }
                double inv = 1.0 / a[c][c];
                for (int j = 0; j < 8; ++j) a[c][j] *= inv;
                for (int r = 0; r < 4; ++r) if (r != c) {
                    double f = a[r][c];
                    for (int j = 0; j < 8; ++j) a[r][j] -= f * a[c][j];
                }
            }
            for (int i = 0; i < 4; ++i)
                for (int j = 0; j < 4; ++j) {
                    float v = (float)a[i][4 + j];
                    P.calib[i * 4 + j] = v;
                    s_calib[i * 4 + j] = v;
                }
        }
        // ---- select: 2-pass (no register cache -> no spill) ----
        int n = P.n;
        int PT = ((n + 255) / 256 + 3) & ~3;
        int PT4 = PT >> 2;
        int st = tid * PT;
        int lane = tid & 63, wid = tid >> 6;
        int c = 0;
        for (int j = 0; j < PT4; ++j) {
            int s = st + j * 4;
            if (s + 4 <= n) {
                float4 v = *(const float4*)&P.clsL[s];
                c += (v.x > SEL_THR) + (v.y > SEL_THR) + (v.z > SEL_THR) + (v.w > SEL_THR);
            } else {
                for (int e = 0; e < 4; ++e) { int ss = s + e; if (ss < n) c += (P.clsL[ss] > SEL_THR); }
            }
        }
        int incl = c;
#pragma unroll
        for (int o = 1; o < 64; o <<= 1) {
            int u = __shfl_up(incl, o, 64);
            if (lane >= o) incl += u;
        }
        if (lane == 63) warpCnt[wid] = incl;
        __syncthreads();                 // warpCnt + s_calib ready
        int base = 0;
        for (int w2 = 0; w2 < wid; ++w2) base += warpCnt[w2];
        int pos = base + incl - c;
        for (int j = 0; j < PT4; ++j) {
            int s = st + j * 4;
            if (s + 4 <= n) {
                float4 v = *(const float4*)&P.clsL[s];
                if (v.x > SEL_THR) P.bbox[pos++] = (s + 0) / 3;
                if (v.y > SEL_THR) P.bbox[pos++] = (s + 1) / 3;
                if (v.z > SEL_THR) P.bbox[pos++] = (s + 2) / 3;
                if (v.w > SEL_THR) P.bbox[pos++] = (s + 3) / 3;
            } else {
                for (int e = 0; e < 4; ++e) {
                    int ss = s + e;
                    if (ss < n && P.clsL[ss] > SEL_THR) P.bbox[pos++] = ss / 3;
                }
            }
        }
        if (tid == 0) {
            int t = 0;
            for (int w2 = 0; w2 < 4; ++w2) t += warpCnt[w2];
            *P.cnt = t;
        }
        // ---- bvec ----
#pragma unroll
        for (int which = 0; which < 2; ++which) {
            const float* W = which ? P.W1 : P.W0;
            const float* b = which ? P.b1 : P.b0;
            float* o       = which ? P.bvec1 : P.bvec0;
            float s = b[tid];
#pragma unroll
            for (int u = 0; u < 9; ++u) {
                float r = s_calib[(u / 3) * 4 + (u % 3)];
                s += r * W[(EMBED + u) * EMBED + tid];
            }
            o[tid] = s;
        }
    } else if (bid < PREPB) {
        // ---- W transpose -> bf16, 64x64 tile ----
        int idx0 = bid - 1;
        int which = idx0 >> 4;
        int t = idx0 & 15;
        int k0 = (t >> 2) * 64, c0 = (t & 3) * 64;
        const float* W = which ? P.W1 : P.W0;
        __bf16* Wt     = which ? P.Wt1 : P.Wt0;
#pragma unroll
        for (int i = 0; i < 16; ++i) {
            int idx = i * 256 + tid;
            int kk = idx >> 6, cc = idx & 63;
            T[kk][cc] = W[(size_t)(k0 + kk) * EMBED + c0 + cc];
        }
        __syncthreads();
#pragma unroll
        for (int i = 0; i < 16; ++i) {
            int idx = i * 256 + tid;
            int cc = idx >> 6, kk = idx & 63;
            Wt[(size_t)(c0 + cc) * EMBED + k0 + kk] = (__bf16)T[kk][cc];
        }
    } else {
        // ---- veh copies: chunked grid-stride ----
        int nb = GRID - PREPB;
        for (int u = bid - PREPB; u < P.cstart[5]; u += nb) {
            int j = 0;
            while (u >= P.cstart[j + 1]) ++j;
            int lc = u - P.cstart[j];
            int b4 = lc * CHUNK4;
            const float* src = P.vsrc[j];
#pragma unroll
            for (int t = 0; t < 16; ++t) {
                int i4 = b4 + t * 256 + tid;
                if (i4 < P.n4[j]) {
                    float4 v = *(const float4*)&src[(size_t)i4 * 4];
                    size_t d;
                    if (P.layStride[j]) {
                        int l = i4 / P.perLay4[j];
                        int r = i4 - l * P.perLay4[j];
                        d = (size_t)P.vdst[j] + (size_t)l * P.layStride[j] + (size_t)r * 4;
                    } else {
                        d = (size_t)P.vdst[j] + (size_t)i4 * 4;
                    }
                    *(float4*)&out[d] = v;
                }
            }
        }
    }

    // ======================= GRID BARRIER =======================
    __threadfence();                         // release phase-1 writes (agent scope)
    __syncthreads();
    if (tid == 0) {
        __hip_atomic_fetch_add(P.bar, 1, __ATOMIC_ACQ_REL, __HIP_MEMORY_SCOPE_AGENT);
        while (__hip_atomic_load(P.bar, __ATOMIC_ACQUIRE, __HIP_MEMORY_SCOPE_AGENT) < GRID) {
            __builtin_amdgcn_s_sleep(8);
        }
    }
    __syncthreads();

    // ======================= PHASE 2 =======================
    if (P.K > 0) {
        int totU = 2 * P.nT + 3 * P.gblk;
        for (int u = bid; u < totU; u += GRID) {
            if (u < 2 * P.nT) {
                int g = (u >= P.nT);
                int lb = g ? u - P.nT : u;
                gemm_block(g ? P.q1 : P.q0, g ? P.Wt1 : P.Wt0, g ? P.bvec1 : P.bvec0,
                           P.bbox, out, P.NI, P.K, g ? P.gemmOff1 : P.gemmOff0, lb);
            } else {
                int v = u - 2 * P.nT;
                int y = v / P.gblk;
                int lb = v - y * P.gblk;
                int k = lb * 256 + tid;
                if (k < P.K) {
                    int box = P.bbox[k]; box = max(0, min(box, P.NI - 1));
                    if (y == 0) {              // inf classes gather
#pragma unroll
                        for (int l = 0; l < LL; ++l) {
                            const float* s = P.icls + ((size_t)l * P.NI + box) * 3;
                            size_t d = (size_t)P.dcls + ((size_t)l * P.N + P.NV) * 3 + (size_t)k * 3;
                            out[d + 0] = s[0]; out[d + 1] = s[1]; out[d + 2] = s[2];
                        }
                    } else if (y == 1) {       // inf coords gather+transform
                        float c00 = P.calib[0], c01 = P.calib[1], c03 = P.calib[3];
                        float c10 = P.calib[4], c11 = P.calib[5], c13 = P.calib[7];
                        float zx = P.calib[2] * -5.0f, zy = P.calib[6] * -5.0f;
#pragma unroll
                        for (int l = 0; l < LL; ++l) {
                            float4 s = *(const float4*)&P.icoord[((size_t)l * P.NI + box) * 4];
                            float X = s.x * 102.4f;
                            float Y = s.y * 102.4f - 51.2f;
                            float tx = c00 * X + c01 * Y + zx + c03;
                            float ty = c10 * X + c11 * Y + zy + c13;
                            float4 vv = make_float4((tx + 51.2f) * (1.0f / 102.4f),
                                                    (ty + 51.2f) * (1.0f / 102.4f), s.z, s.w);
                            *(float4*)&out[(size_t)P.dcoord + ((size_t)l * P.N + P.NV + k) * 4] = vv;
                        }
                    } else {                   // inf reference
                        float4 s = *(const float4*)&P.iref[(size_t)box * 4];
                        float sx = 1.0f / (1.0f + expf(-s.x));
                        float sy = 1.0f / (1.0f + expf(-s.y));
                        float X = sx * 102.4f;
                        float Y = sy * 102.4f - 51.2f;
                        float tx = P.calib[0] * X + P.calib[1] * Y + P.calib[2] * -1.0f + P.calib[3];
                        float ty = P.calib[4] * X + P.calib[5] * Y + P.calib[6] * -1.0f + P.calib[7];
                        float4 vv = make_float4(inv_sig((tx + 51.2f) * (1.0f / 102.4f)),
                                                inv_sig((ty + 51.2f) * (1.0f / 102.4f)), s.z, s.w);
                        *(float4*)&out[(size_t)P.dref + ((size_t)P.NV + k) * 4] = vv;
                    }
                }
            }
        }
    }
}

extern "C" void kernel_launch(void* const* d_in, const int* in_sizes, int n_in,
                              void* d_out, int out_size, void* d_ws, size_t ws_size,
                              hipStream_t stream) {
    const float* inf_cls   = (const float*)d_in[0];
    const float* inf_coord = (const float*)d_in[1];
    const float* inf_q     = (const float*)d_in[2];
    const float* inf_qp    = (const float*)d_in[3];
    const float* inf_ref   = (const float*)d_in[4];
    const float* veh_cls   = (const float*)d_in[5];
    const float* veh_coord = (const float*)d_in[6];
    const float* veh_q     = (const float*)d_in[7];
    const float* veh_qp    = (const float*)d_in[8];
    const float* veh_ref   = (const float*)d_in[9];
    const float* rt        = (const float*)d_in[10];
    const float* W0        = (const float*)d_in[11];
    const float* b0        = (const float*)d_in[12];
    const float* W1        = (const float*)d_in[13];
    const float* b1        = (const float*)d_in[14];
    float* out = (float*)d_out;

    int NI = in_sizes[0] / (LL * 3);
    int NV = in_sizes[5] / (LL * 3);
    int N  = out_size / 558;
    int K  = N - NV;

    int off_cls   = 0;
    int off_coord = LL * N * 3;
    int off_q     = off_coord + LL * N * 4;
    int off_qp    = off_q + N * EMBED;
    int off_ref   = off_qp + N * EMBED;

    char* ws = (char*)d_ws;
    float* calib = (float*)(ws);
    float* bvec0 = (float*)(ws + 128);
    float* bvec1 = (float*)(ws + 1152);
    int*   cnt   = (int*)(ws + 2176);
    int*   bar   = (int*)(ws + 2240);
    int*   bbox  = (int*)(ws + 2304);
    __bf16* Wt0  = (__bf16*)(ws + 131072);
    __bf16* Wt1  = (__bf16*)(ws + 262144);

    // zero the barrier counter each call (graph-legal async memset)
    hipMemsetAsync(bar, 0, sizeof(int), stream);

    PlanAll P;
    P.clsL = inf_cls + (size_t)(LL - 1) * NI * 3;
    P.n = NI * 3;
    P.rt = rt; P.W0 = W0; P.W1 = W1; P.b0 = b0; P.b1 = b1;
    P.vsrc[0] = veh_q;     P.vsrc[1] = veh_qp;
    P.vsrc[2] = veh_cls;   P.vsrc[3] = veh_coord; P.vsrc[4] = veh_ref;
    P.icls = inf_cls; P.icoord = inf_coord; P.iref = inf_ref;
    P.q0 = inf_q; P.q1 = inf_qp;
    P.calib = calib; P.bbox = bbox; P.cnt = cnt; P.bar = bar;
    P.Wt0 = Wt0; P.Wt1 = Wt1; P.bvec0 = bvec0; P.bvec1 = bvec1;
    P.n4[0] = NV * EMBED / 4;   P.n4[1] = NV * EMBED / 4;
    P.n4[2] = LL * NV * 3 / 4;  P.n4[3] = LL * NV * 4 / 4;  P.n4[4] = NV * 4 / 4;
    P.vdst[0] = off_q;   P.vdst[1] = off_qp;
    P.vdst[2] = off_cls; P.vdst[3] = off_coord; P.vdst[4] = off_ref;
    P.perLay4[0] = P.n4[0]; P.perLay4[1] = P.n4[1];
    P.perLay4[2] = NV * 3 / 4; P.perLay4[3] = NV * 4 / 4; P.perLay4[4] = P.n4[4];
    P.layStride[0] = 0; P.layStride[1] = 0;
    P.layStride[2] = N * 3; P.layStride[3] = N * 4; P.layStride[4] = 0;
    P.cstart[0] = 0;
    for (int j = 0; j < 5; ++j)
        P.cstart[j + 1] = P.cstart[j] + (P.n4[j] + CHUNK4 - 1) / CHUNK4;
    P.nT   = (K > 0) ? (K + 63) / 64 : 0;
    P.gblk = (K > 0) ? (K + 255) / 256 : 0;
    P.gemmOff0 = off_q + NV * EMBED;
    P.gemmOff1 = off_qp + NV * EMBED;
    P.dcls = off_cls; P.dcoord = off_coord; P.dref = off_ref;
    P.K = K; P.NI = NI; P.NV = NV; P.N = N;

    hipLaunchKernelGGL(k_all, dim3(GRID), dim3(256), 0, stream, P, out);
}